// Round 12
// baseline (514.125 us; speedup 1.0000x reference)
//
#include <hip/hip_runtime.h>
#include <hip/hip_bf16.h>

// GraphSAGE 3-layer, eval mode.
// Round 12: merged scan (bsum+bapply -> k_scan_apply, one dispatch);
// gather unroll 8 + nontemporal agg store (protect L3-resident featbf);
// nontemporal csr scatter in fill. 10 dispatches.

static constexpr int kN1 = 100000, kN2 = 20000, kN3 = 4096;
static constexpr int kE0 = 1500000, kE1 = 200000, kE2 = 40960;

using bf8v  = __attribute__((ext_vector_type(8))) short;   // 8 bf16 (4 VGPR)
using f32x4 = __attribute__((ext_vector_type(4))) float;   // MFMA acc
using u32x4 = __attribute__((ext_vector_type(4))) unsigned int;

__device__ __forceinline__ unsigned short f2bu(float f) {
    __hip_bfloat16 h = __float2bfloat16(f);
    return *reinterpret_cast<unsigned short*>(&h);
}
__device__ __forceinline__ float bu2f_lo(unsigned u) {
    unsigned b = u << 16; return *reinterpret_cast<float*>(&b);
}
__device__ __forceinline__ float bu2f_hi(unsigned u) {
    unsigned b = u & 0xffff0000u; return *reinterpret_cast<float*>(&b);
}

// section block counts
static constexpr int CB  = 50000;                 // cast: 12.8M uint4 / 256
static constexpr int C0B = (kE0 + 255) / 256;     // 5860
static constexpr int C1B = (kE1 + 255) / 256;     // 782
static constexpr int C2B = (kE2 + 255) / 256;     // 160
static constexpr int PW0B = 512, PW1B = 512, PW2B = 256;
// scan geometry (int4s per layer)
static constexpr int M4_0 = kN1 / 4, M4_1 = kN2 / 4, M4_2 = kN3 / 4;
static constexpr int B0 = (M4_0 + 255) / 256;     // 98
static constexpr int B1 = (M4_1 + 255) / 256;     // 20
static constexpr int B2 = (M4_2 + 255) / 256;     // 4
static constexpr int BSCAN = B0 + B1 + B2;        // 122
// zero region: cnt0|cnt1|cnt2 = 496384 B
static constexpr int ZN4 = 496384 / 16;           // 31024 int4
static constexpr int ZB  = (ZN4 + 255) / 256;     // 122
// fill geometry: 8 edges/thread
static constexpr int ET = kE0 + kE1 + kE2;        // 1740960
static constexpr int FB = (ET / 8 + 255) / 256;   // 851 blocks

// ---------------- zero cnt region ----------------
__global__ __launch_bounds__(256) void k_zero(int4* __restrict__ p)
{
    int i = blockIdx.x * 256 + threadIdx.x;
    if (i < ZN4) p[i] = make_int4(0, 0, 0, 0);
}

// ---------------- phase 0: cast || count+rank x3 || weight-prep x3 ----------
template <bool BIG>
__global__ __launch_bounds__(256) void k_phase0(
    const float4* __restrict__ feat4, uint4* __restrict__ featbf,
    const int* __restrict__ e0d, const int* __restrict__ e1d,
    const int* __restrict__ e2d,
    int* __restrict__ cnt0, int* __restrict__ cnt1, int* __restrict__ cnt2,
    int* __restrict__ er0, int* __restrict__ er1, int* __restrict__ er2,
    const float* __restrict__ ws0, const float* __restrict__ wn0,
    const float* __restrict__ ws1, const float* __restrict__ wn1,
    const float* __restrict__ ws2, const float* __restrict__ wn2,
    unsigned short* __restrict__ wt0, unsigned short* __restrict__ wt1,
    unsigned short* __restrict__ wt2)
{
    int b = blockIdx.x;
    const int tid = threadIdx.x;
    if (BIG) {
        if (b < CB) {
            int i = b * 256 + tid;
            float4 a = feat4[2 * i], c = feat4[2 * i + 1];
            uint4 o;
            o.x = (unsigned)f2bu(a.x) | ((unsigned)f2bu(a.y) << 16);
            o.y = (unsigned)f2bu(a.z) | ((unsigned)f2bu(a.w) << 16);
            o.z = (unsigned)f2bu(c.x) | ((unsigned)f2bu(c.y) << 16);
            o.w = (unsigned)f2bu(c.z) | ((unsigned)f2bu(c.w) << 16);
            featbf[i] = o;
            return;
        }
        b -= CB;
    }
    if (b < C0B) {
        int e = b * 256 + tid;
        if (e < kE0) er0[e] = atomicAdd(cnt0 + e0d[e], 1);
        return;
    }
    b -= C0B;
    if (b < C1B) {
        int e = b * 256 + tid;
        if (e < kE1) er1[e] = atomicAdd(cnt1 + e1d[e], 1);
        return;
    }
    b -= C1B;
    if (b < C2B) {
        int e = b * 256 + tid;
        if (e < kE2) er2[e] = atomicAdd(cnt2 + e2d[e], 1);
        return;
    }
    b -= C2B;
    if (b < PW0B) {
        int idx = b * 256 + tid;
        int n = idx >> 9, k = idx & 511;
        wt0[idx] = f2bu(k < 256 ? ws0[k * 256 + n] : wn0[(k - 256) * 256 + n]);
        return;
    }
    b -= PW0B;
    if (b < PW1B) {
        int idx = b * 256 + tid;
        int n = idx >> 9, k = idx & 511;
        wt1[idx] = f2bu(k < 256 ? ws1[k * 256 + n] : wn1[(k - 256) * 256 + n]);
        return;
    }
    b -= PW1B;
    {
        int idx = b * 256 + tid;
        int n = idx >> 9, k = idx & 511;
        wt2[idx] = f2bu(k < 256 ? ws2[k * 128 + n] : wn2[(k - 256) * 128 + n]);
    }
}

// ---------------- merged scan+apply: rp = exclusive start offsets -----------
// Each block redundantly computes its predecessor sum directly from cnt
// (coalesced int4 reads, <=400KB/block) -- replaces the bsum dispatch.
__global__ __launch_bounds__(256) void k_scan_apply(
    const int* __restrict__ cnt0, const int* __restrict__ cnt1,
    const int* __restrict__ cnt2,
    int* __restrict__ rp0, int* __restrict__ rp1, int* __restrict__ rp2)
{
    const int* cnt; int* rp; int lb, M4;
    int b = blockIdx.x;
    if (b < B0)            { cnt = cnt0; rp = rp0; lb = b;           M4 = M4_0; }
    else if (b < B0 + B1)  { cnt = cnt1; rp = rp1; lb = b - B0;      M4 = M4_1; }
    else                   { cnt = cnt2; rp = rp2; lb = b - B0 - B1; M4 = M4_2; }
    const int tid = threadIdx.x;
    const int lane = tid & 63;
    const int wid = tid >> 6;
    __shared__ int wpre[4];
    __shared__ int wsum[4];
    __shared__ int wexcl[4];
    __shared__ int blockbase;
    const int4* c4 = reinterpret_cast<const int4*>(cnt);
    // predecessor sum: cnt[0 .. lb*1024)
    int pre = 0;
    for (int i = tid; i < lb * 256; i += 256) {
        int4 v = c4[i];
        pre += v.x + v.y + v.z + v.w;
    }
#pragma unroll
    for (int off = 32; off > 0; off >>= 1) pre += __shfl_down(pre, off, 64);
    if (lane == 0) wpre[wid] = pre;
    // own-chunk scan
    int idx = lb * 256 + tid;
    int4 v = make_int4(0, 0, 0, 0);
    if (idx < M4) v = c4[idx];
    int ts = v.x + v.y + v.z + v.w;
    int incl = ts;
#pragma unroll
    for (int off = 1; off < 64; off <<= 1) {
        int t = __shfl_up(incl, off, 64);
        if (lane >= off) incl += t;
    }
    if (lane == 63) wsum[wid] = incl;
    __syncthreads();
    if (tid == 0) blockbase = wpre[0] + wpre[1] + wpre[2] + wpre[3];
    if (tid < 4) {
        int e = 0;
        for (int i = 0; i < tid; ++i) e += wsum[i];
        wexcl[tid] = e;
    }
    __syncthreads();
    if (idx < M4) {
        int base = blockbase + wexcl[wid] + (incl - ts);
        int4 o;
        o.x = base;
        o.y = base + v.x;
        o.z = base + v.x + v.y;
        o.w = base + v.x + v.y + v.z;
        reinterpret_cast<int4*>(rp)[idx] = o;
    }
}

// ---------------- fill: NO atomics. csr[rp[d]+erank[e]] = src[e] ------------
__global__ __launch_bounds__(256) void k_fill_all(
    const int* __restrict__ e0s, const int* __restrict__ e0d,
    const int* __restrict__ e1s, const int* __restrict__ e1d,
    const int* __restrict__ e2s, const int* __restrict__ e2d,
    const int* __restrict__ er0, const int* __restrict__ er1,
    const int* __restrict__ er2,
    const int* __restrict__ rp0, const int* __restrict__ rp1,
    const int* __restrict__ rp2,
    int* __restrict__ csr0, int* __restrict__ csr1, int* __restrict__ csr2)
{
    const int t = blockIdx.x * 256 + threadIdx.x;
    const int T = FB * 256;
    int ss[8], dd[8], rr[8], pos[8];
    const int* rpp[8];
    int* cp[8];
    bool ok[8];
#pragma unroll
    for (int i = 0; i < 8; ++i) {
        int e = t + i * T;
        ok[i] = e < ET;
        ss[i] = 0; dd[i] = 0; rr[i] = 0; rpp[i] = rp0; cp[i] = csr0;
        if (ok[i]) {
            if (e < kE0) {
                ss[i] = e0s[e]; dd[i] = e0d[e]; rr[i] = er0[e];
            } else if (e < kE0 + kE1) {
                int le = e - kE0;
                ss[i] = e1s[le]; dd[i] = e1d[le]; rr[i] = er1[le];
                rpp[i] = rp1; cp[i] = csr1;
            } else {
                int le = e - kE0 - kE1;
                ss[i] = e2s[le]; dd[i] = e2d[le]; rr[i] = er2[le];
                rpp[i] = rp2; cp[i] = csr2;
            }
        }
    }
#pragma unroll
    for (int i = 0; i < 8; ++i)
        if (ok[i]) pos[i] = rpp[i][dd[i]];     // 8 independent random loads
#pragma unroll
    for (int i = 0; i < 8; ++i)
        if (ok[i]) __builtin_nontemporal_store(ss[i], &cp[i][pos[i] + rr[i]]);
}

// ---------------- gather segment-mean -> bf16 (bf16 src) --------------------
// rp_start[d] = start offset (unmutated), end = start + cnt[d]
__global__ __launch_bounds__(256) void k_gather_agg_b(
    const unsigned short* __restrict__ h, const int* __restrict__ csr,
    const int* __restrict__ rp_start, const int* __restrict__ cnt,
    unsigned short* __restrict__ agg, int M)
{
    int d = blockIdx.x * 4 + (threadIdx.x >> 6);
    if (d >= M) return;
    const int lane = threadIdx.x & 63;
    const int half = lane >> 5;
    const int l32 = lane & 31;
    int c = cnt[d], start = rp_start[d], end = start + c;
    float a[8] = {0.f, 0.f, 0.f, 0.f, 0.f, 0.f, 0.f, 0.f};
    for (int chunk = start; chunk < end; chunk += 64) {
        int n = end - chunk; if (n > 64) n = 64;
        int mysrc = (lane < n) ? csr[chunk + lane] : 0;
#pragma unroll 8
        for (int e = 0; e < n; e += 2) {
            int ie = e + half;
            int s = __shfl(mysrc, ie, 64);
            if (ie < n) {
                uint4 v = *reinterpret_cast<const uint4*>(
                    h + (size_t)s * 256 + l32 * 8);
                a[0] += bu2f_lo(v.x); a[1] += bu2f_hi(v.x);
                a[2] += bu2f_lo(v.y); a[3] += bu2f_hi(v.y);
                a[4] += bu2f_lo(v.z); a[5] += bu2f_hi(v.z);
                a[6] += bu2f_lo(v.w); a[7] += bu2f_hi(v.w);
            }
        }
    }
#pragma unroll
    for (int j = 0; j < 8; ++j) a[j] += __shfl(a[j], lane ^ 32, 64);
    if (half == 0) {
        float inv = 1.0f / (float)(c > 1 ? c : 1);
        u32x4 o;
        o[0] = (unsigned)f2bu(a[0] * inv) | ((unsigned)f2bu(a[1] * inv) << 16);
        o[1] = (unsigned)f2bu(a[2] * inv) | ((unsigned)f2bu(a[3] * inv) << 16);
        o[2] = (unsigned)f2bu(a[4] * inv) | ((unsigned)f2bu(a[5] * inv) << 16);
        o[3] = (unsigned)f2bu(a[6] * inv) | ((unsigned)f2bu(a[7] * inv) << 16);
        // nontemporal: don't evict L3-resident feature rows with this stream
        __builtin_nontemporal_store(
            o, reinterpret_cast<u32x4*>(agg + (size_t)d * 256 + l32 * 8));
    }
}

// f32-src fallback (small-ws path)
__global__ __launch_bounds__(256) void k_gather_agg_f(
    const float* __restrict__ h, const int* __restrict__ csr,
    const int* __restrict__ rp_start, const int* __restrict__ cnt,
    unsigned short* __restrict__ agg, int M)
{
    int d = blockIdx.x * 4 + (threadIdx.x >> 6);
    if (d >= M) return;
    int lane = threadIdx.x & 63;
    int c = cnt[d], start = rp_start[d], end = start + c;
    float a0 = 0.f, a1 = 0.f, a2 = 0.f, a3 = 0.f;
    for (int chunk = start; chunk < end; chunk += 64) {
        int n = end - chunk; if (n > 64) n = 64;
        int mysrc = (lane < n) ? csr[chunk + lane] : 0;
#pragma unroll 4
        for (int e = 0; e < n; ++e) {
            int s = __shfl(mysrc, e, 64);
            float4 v = reinterpret_cast<const float4*>(h + (size_t)s * 256)[lane];
            a0 += v.x; a1 += v.y; a2 += v.z; a3 += v.w;
        }
    }
    float inv = 1.0f / (float)(c > 1 ? c : 1);
    ushort4 o;
    o.x = f2bu(a0 * inv); o.y = f2bu(a1 * inv);
    o.z = f2bu(a2 * inv); o.w = f2bu(a3 * inv);
    *reinterpret_cast<ushort4*>(agg + (size_t)d * 256 + lane * 4) = o;
}

// ---------------- MFMA dual-GEMM: out = act([A0|A1] @ WT^T + b) ----------------
template <int ACT, bool A0F32, bool OUTF32>
__global__ __launch_bounds__(256) void k_mfma_gemm(
    const void* __restrict__ A0v, const unsigned short* __restrict__ A1,
    const unsigned short* __restrict__ WT, const float* __restrict__ bias,
    void* __restrict__ outv, int M, int N)
{
    __shared__ unsigned short sA[128 * 72];
    __shared__ unsigned short sB[128 * 72];
    const int tid = threadIdx.x;
    const int lane = tid & 63;
    const int w = tid >> 6;
    const int wr = w >> 1, wc = w & 1;
    const int row0 = blockIdx.x * 128;
    const int col0 = blockIdx.y * 128;

    f32x4 acc[4][4] = {};

    for (int p = 0; p < 8; ++p) {
        const int kc0 = p * 64;
        if (kc0 < 256) {
            if constexpr (A0F32) {
                const float* src = (const float*)A0v;
#pragma unroll
                for (int ps = 0; ps < 8; ++ps) {
                    int flat = (ps * 256 + tid) * 4;
                    int r = flat >> 6, cc = flat & 63;
                    int row = row0 + r; row = row < M ? row : M - 1;
                    float4 v = *reinterpret_cast<const float4*>(
                        src + (size_t)row * 256 + kc0 + cc);
                    ushort4 b4;
                    b4.x = f2bu(v.x); b4.y = f2bu(v.y);
                    b4.z = f2bu(v.z); b4.w = f2bu(v.w);
                    *reinterpret_cast<ushort4*>(&sA[r * 72 + cc]) = b4;
                }
            } else {
                const unsigned short* src = (const unsigned short*)A0v;
#pragma unroll
                for (int ps = 0; ps < 4; ++ps) {
                    int f8 = ps * 256 + tid;
                    int r = f8 >> 3, c8 = f8 & 7;
                    int row = row0 + r; row = row < M ? row : M - 1;
                    uint4 v = *reinterpret_cast<const uint4*>(
                        src + (size_t)row * 256 + kc0 + c8 * 8);
                    *reinterpret_cast<uint4*>(&sA[r * 72 + c8 * 8]) = v;
                }
            }
        } else {
#pragma unroll
            for (int ps = 0; ps < 4; ++ps) {
                int f8 = ps * 256 + tid;
                int r = f8 >> 3, c8 = f8 & 7;
                int row = row0 + r; row = row < M ? row : M - 1;
                uint4 v = *reinterpret_cast<const uint4*>(
                    A1 + (size_t)row * 256 + (kc0 - 256) + c8 * 8);
                *reinterpret_cast<uint4*>(&sA[r * 72 + c8 * 8]) = v;
            }
        }
#pragma unroll
        for (int ps = 0; ps < 4; ++ps) {
            int f8 = ps * 256 + tid;
            int r = f8 >> 3, c8 = f8 & 7;
            uint4 v = *reinterpret_cast<const uint4*>(
                WT + (size_t)(col0 + r) * 512 + kc0 + c8 * 8);
            *reinterpret_cast<uint4*>(&sB[r * 72 + c8 * 8]) = v;
        }
        __syncthreads();
#pragma unroll
        for (int ks = 0; ks < 64; ks += 32) {
            const int lr = lane & 15;
            const int kk = ks + (lane >> 4) * 8;
            bf8v af[4], bfr[4];
#pragma unroll
            for (int m = 0; m < 4; ++m)
                af[m] = *reinterpret_cast<const bf8v*>(
                    &sA[(wr * 64 + m * 16 + lr) * 72 + kk]);
#pragma unroll
            for (int n = 0; n < 4; ++n)
                bfr[n] = *reinterpret_cast<const bf8v*>(
                    &sB[(wc * 64 + n * 16 + lr) * 72 + kk]);
#pragma unroll
            for (int m = 0; m < 4; ++m)
#pragma unroll
                for (int n = 0; n < 4; ++n)
                    acc[m][n] = __builtin_amdgcn_mfma_f32_16x16x32_bf16(
                        af[m], bfr[n], acc[m][n], 0, 0, 0);
        }
        __syncthreads();
    }

    const int lc = lane & 15;
    const int lr4 = (lane >> 4) * 4;
#pragma unroll
    for (int n = 0; n < 4; ++n) {
        int col = col0 + wc * 64 + n * 16 + lc;
        float bb = bias[col];
#pragma unroll
        for (int m = 0; m < 4; ++m) {
#pragma unroll
            for (int j = 0; j < 4; ++j) {
                int row = row0 + wr * 64 + m * 16 + lr4 + j;
                if (row < M) {
                    float v = acc[m][n][j] + bb;
                    if (ACT) v = fmaxf(v, 0.f);
                    if constexpr (OUTF32)
                        ((float*)outv)[(size_t)row * N + col] = v;
                    else
                        ((unsigned short*)outv)[(size_t)row * N + col] = f2bu(v);
                }
            }
        }
    }
}

extern "C" void kernel_launch(void* const* d_in, const int* in_sizes, int n_in,
                              void* d_out, int out_size, void* d_ws, size_t ws_size,
                              hipStream_t stream) {
    const float* feat = (const float*)d_in[0];
    const int* e0s = (const int*)d_in[1];
    const int* e0d = (const int*)d_in[2];
    const int* e1s = (const int*)d_in[3];
    const int* e1d = (const int*)d_in[4];
    const int* e2s = (const int*)d_in[5];
    const int* e2d = (const int*)d_in[6];
    const float* ws0 = (const float*)d_in[7];
    const float* wn0 = (const float*)d_in[8];
    const float* b0 = (const float*)d_in[9];
    const float* ws1 = (const float*)d_in[10];
    const float* wn1 = (const float*)d_in[11];
    const float* b1 = (const float*)d_in[12];
    const float* ws2 = (const float*)d_in[13];
    const float* wn2 = (const float*)d_in[14];
    const float* b2 = (const float*)d_in[15];
    float* out = (float*)d_out;

    char* base = (char*)d_ws;
    const bool big = ws_size >= 345000000ull;
    unsigned short* featbf = nullptr;
    size_t off = 0;
    if (big) { featbf = (unsigned short*)base; off += 204800000ull; }
    unsigned short* aggb = (unsigned short*)(base + off); off += 51200000ull;
    unsigned short* h1b  = (unsigned short*)(base + off); off += 51200000ull;
    unsigned short* h2b  = (unsigned short*)(base + off); off += 10240000ull;
    unsigned short* wt0  = (unsigned short*)(base + off); off += 262144ull;
    unsigned short* wt1  = (unsigned short*)(base + off); off += 262144ull;
    unsigned short* wt2  = (unsigned short*)(base + off); off += 131072ull;
    int* csr0 = (int*)(base + off); off += 6000000ull;
    int* csr1 = (int*)(base + off); off += 800000ull;
    int* csr2 = (int*)(base + off); off += 163840ull;
    // zeroed region: cnt0|cnt1|cnt2 (496384 B)
    int* cnt0 = (int*)(base + off); off += 400000ull;
    int* cnt1 = (int*)(base + off); off += 80000ull;
    int* cnt2 = (int*)(base + off); off += 16384ull;
    int* rp0  = (int*)(base + off); off += 400000ull;
    int* rp1  = (int*)(base + off); off += 80000ull;
    int* rp2  = (int*)(base + off); off += 16384ull;
    int* er0  = (int*)(base + off); off += 6000000ull;
    int* er1  = (int*)(base + off); off += 800000ull;
    int* er2  = (int*)(base + off); off += 163840ull;

    k_zero<<<ZB, 256, 0, stream>>>((int4*)cnt0);

    if (big)
        k_phase0<true><<<CB + C0B + C1B + C2B + PW0B + PW1B + PW2B, 256, 0, stream>>>(
            (const float4*)feat, (uint4*)featbf, e0d, e1d, e2d,
            cnt0, cnt1, cnt2, er0, er1, er2,
            ws0, wn0, ws1, wn1, ws2, wn2, wt0, wt1, wt2);
    else
        k_phase0<false><<<C0B + C1B + C2B + PW0B + PW1B + PW2B, 256, 0, stream>>>(
            nullptr, nullptr, e0d, e1d, e2d,
            cnt0, cnt1, cnt2, er0, er1, er2,
            ws0, wn0, ws1, wn1, ws2, wn2, wt0, wt1, wt2);

    k_scan_apply<<<BSCAN, 256, 0, stream>>>(
        cnt0, cnt1, cnt2, rp0, rp1, rp2);
    k_fill_all<<<FB, 256, 0, stream>>>(
        e0s, e0d, e1s, e1d, e2s, e2d,
        er0, er1, er2, rp0, rp1, rp2, csr0, csr1, csr2);

    // ---- layer 0 ----
    if (big) {
        k_gather_agg_b<<<(kN1 + 3) / 4, 256, 0, stream>>>(
            featbf, csr0, rp0, cnt0, aggb, kN1);
        k_mfma_gemm<1, false, false><<<dim3(782, 2), 256, 0, stream>>>(
            featbf, aggb, wt0, b0, h1b, kN1, 256);
    } else {
        k_gather_agg_f<<<(kN1 + 3) / 4, 256, 0, stream>>>(
            feat, csr0, rp0, cnt0, aggb, kN1);
        k_mfma_gemm<1, true, false><<<dim3(782, 2), 256, 0, stream>>>(
            feat, aggb, wt0, b0, h1b, kN1, 256);
    }

    // ---- layer 1 ----
    k_gather_agg_b<<<(kN2 + 3) / 4, 256, 0, stream>>>(
        h1b, csr1, rp1, cnt1, aggb, kN2);
    k_mfma_gemm<1, false, false><<<dim3(157, 2), 256, 0, stream>>>(
        h1b, aggb, wt1, b1, h2b, kN2, 256);

    // ---- layer 2 ----
    k_gather_agg_b<<<(kN3 + 3) / 4, 256, 0, stream>>>(
        h2b, csr2, rp2, cnt2, aggb, kN3);
    k_mfma_gemm<0, false, true><<<dim3(32, 1), 256, 0, stream>>>(
        h2b, aggb, wt2, b2, out, kN3, 128);
}

// Round 13
// 486.714 us; speedup vs baseline: 1.0563x; 1.0563x over previous
//
#include <hip/hip_runtime.h>
#include <hip/hip_bf16.h>

// GraphSAGE 3-layer, eval mode.
// Round 13: controlled revert of round-12's bundle. Gather back to unroll-4 +
// regular stores (round-11 exact); fill back to regular stores (round-11
// exact). KEEP merged k_scan_apply (the only round-12 change retained) ->
// clean A/B attribution. 10 dispatches.

static constexpr int kN1 = 100000, kN2 = 20000, kN3 = 4096;
static constexpr int kE0 = 1500000, kE1 = 200000, kE2 = 40960;

using bf8v  = __attribute__((ext_vector_type(8))) short;   // 8 bf16 (4 VGPR)
using f32x4 = __attribute__((ext_vector_type(4))) float;   // MFMA acc

__device__ __forceinline__ unsigned short f2bu(float f) {
    __hip_bfloat16 h = __float2bfloat16(f);
    return *reinterpret_cast<unsigned short*>(&h);
}
__device__ __forceinline__ float bu2f_lo(unsigned u) {
    unsigned b = u << 16; return *reinterpret_cast<float*>(&b);
}
__device__ __forceinline__ float bu2f_hi(unsigned u) {
    unsigned b = u & 0xffff0000u; return *reinterpret_cast<float*>(&b);
}

// section block counts
static constexpr int CB  = 50000;                 // cast: 12.8M uint4 / 256
static constexpr int C0B = (kE0 + 255) / 256;     // 5860
static constexpr int C1B = (kE1 + 255) / 256;     // 782
static constexpr int C2B = (kE2 + 255) / 256;     // 160
static constexpr int PW0B = 512, PW1B = 512, PW2B = 256;
// scan geometry (int4s per layer)
static constexpr int M4_0 = kN1 / 4, M4_1 = kN2 / 4, M4_2 = kN3 / 4;
static constexpr int B0 = (M4_0 + 255) / 256;     // 98
static constexpr int B1 = (M4_1 + 255) / 256;     // 20
static constexpr int B2 = (M4_2 + 255) / 256;     // 4
static constexpr int BSCAN = B0 + B1 + B2;        // 122
// zero region: cnt0|cnt1|cnt2 = 496384 B
static constexpr int ZN4 = 496384 / 16;           // 31024 int4
static constexpr int ZB  = (ZN4 + 255) / 256;     // 122
// fill geometry: 8 edges/thread
static constexpr int ET = kE0 + kE1 + kE2;        // 1740960
static constexpr int FB = (ET / 8 + 255) / 256;   // 851 blocks

// ---------------- zero cnt region ----------------
__global__ __launch_bounds__(256) void k_zero(int4* __restrict__ p)
{
    int i = blockIdx.x * 256 + threadIdx.x;
    if (i < ZN4) p[i] = make_int4(0, 0, 0, 0);
}

// ---------------- phase 0: cast || count+rank x3 || weight-prep x3 ----------
template <bool BIG>
__global__ __launch_bounds__(256) void k_phase0(
    const float4* __restrict__ feat4, uint4* __restrict__ featbf,
    const int* __restrict__ e0d, const int* __restrict__ e1d,
    const int* __restrict__ e2d,
    int* __restrict__ cnt0, int* __restrict__ cnt1, int* __restrict__ cnt2,
    int* __restrict__ er0, int* __restrict__ er1, int* __restrict__ er2,
    const float* __restrict__ ws0, const float* __restrict__ wn0,
    const float* __restrict__ ws1, const float* __restrict__ wn1,
    const float* __restrict__ ws2, const float* __restrict__ wn2,
    unsigned short* __restrict__ wt0, unsigned short* __restrict__ wt1,
    unsigned short* __restrict__ wt2)
{
    int b = blockIdx.x;
    const int tid = threadIdx.x;
    if (BIG) {
        if (b < CB) {
            int i = b * 256 + tid;
            float4 a = feat4[2 * i], c = feat4[2 * i + 1];
            uint4 o;
            o.x = (unsigned)f2bu(a.x) | ((unsigned)f2bu(a.y) << 16);
            o.y = (unsigned)f2bu(a.z) | ((unsigned)f2bu(a.w) << 16);
            o.z = (unsigned)f2bu(c.x) | ((unsigned)f2bu(c.y) << 16);
            o.w = (unsigned)f2bu(c.z) | ((unsigned)f2bu(c.w) << 16);
            featbf[i] = o;
            return;
        }
        b -= CB;
    }
    if (b < C0B) {
        int e = b * 256 + tid;
        if (e < kE0) er0[e] = atomicAdd(cnt0 + e0d[e], 1);
        return;
    }
    b -= C0B;
    if (b < C1B) {
        int e = b * 256 + tid;
        if (e < kE1) er1[e] = atomicAdd(cnt1 + e1d[e], 1);
        return;
    }
    b -= C1B;
    if (b < C2B) {
        int e = b * 256 + tid;
        if (e < kE2) er2[e] = atomicAdd(cnt2 + e2d[e], 1);
        return;
    }
    b -= C2B;
    if (b < PW0B) {
        int idx = b * 256 + tid;
        int n = idx >> 9, k = idx & 511;
        wt0[idx] = f2bu(k < 256 ? ws0[k * 256 + n] : wn0[(k - 256) * 256 + n]);
        return;
    }
    b -= PW0B;
    if (b < PW1B) {
        int idx = b * 256 + tid;
        int n = idx >> 9, k = idx & 511;
        wt1[idx] = f2bu(k < 256 ? ws1[k * 256 + n] : wn1[(k - 256) * 256 + n]);
        return;
    }
    b -= PW1B;
    {
        int idx = b * 256 + tid;
        int n = idx >> 9, k = idx & 511;
        wt2[idx] = f2bu(k < 256 ? ws2[k * 128 + n] : wn2[(k - 256) * 128 + n]);
    }
}

// ---------------- merged scan+apply: rp = exclusive start offsets -----------
__global__ __launch_bounds__(256) void k_scan_apply(
    const int* __restrict__ cnt0, const int* __restrict__ cnt1,
    const int* __restrict__ cnt2,
    int* __restrict__ rp0, int* __restrict__ rp1, int* __restrict__ rp2)
{
    const int* cnt; int* rp; int lb, M4;
    int b = blockIdx.x;
    if (b < B0)            { cnt = cnt0; rp = rp0; lb = b;           M4 = M4_0; }
    else if (b < B0 + B1)  { cnt = cnt1; rp = rp1; lb = b - B0;      M4 = M4_1; }
    else                   { cnt = cnt2; rp = rp2; lb = b - B0 - B1; M4 = M4_2; }
    const int tid = threadIdx.x;
    const int lane = tid & 63;
    const int wid = tid >> 6;
    __shared__ int wpre[4];
    __shared__ int wsum[4];
    __shared__ int wexcl[4];
    __shared__ int blockbase;
    const int4* c4 = reinterpret_cast<const int4*>(cnt);
    int pre = 0;
    for (int i = tid; i < lb * 256; i += 256) {
        int4 v = c4[i];
        pre += v.x + v.y + v.z + v.w;
    }
#pragma unroll
    for (int off = 32; off > 0; off >>= 1) pre += __shfl_down(pre, off, 64);
    if (lane == 0) wpre[wid] = pre;
    int idx = lb * 256 + tid;
    int4 v = make_int4(0, 0, 0, 0);
    if (idx < M4) v = c4[idx];
    int ts = v.x + v.y + v.z + v.w;
    int incl = ts;
#pragma unroll
    for (int off = 1; off < 64; off <<= 1) {
        int t = __shfl_up(incl, off, 64);
        if (lane >= off) incl += t;
    }
    if (lane == 63) wsum[wid] = incl;
    __syncthreads();
    if (tid == 0) blockbase = wpre[0] + wpre[1] + wpre[2] + wpre[3];
    if (tid < 4) {
        int e = 0;
        for (int i = 0; i < tid; ++i) e += wsum[i];
        wexcl[tid] = e;
    }
    __syncthreads();
    if (idx < M4) {
        int base = blockbase + wexcl[wid] + (incl - ts);
        int4 o;
        o.x = base;
        o.y = base + v.x;
        o.z = base + v.x + v.y;
        o.w = base + v.x + v.y + v.z;
        reinterpret_cast<int4*>(rp)[idx] = o;
    }
}

// ---------------- fill: NO atomics. csr[rp[d]+erank[e]] = src[e] ------------
// (round-11 exact: regular stores)
__global__ __launch_bounds__(256) void k_fill_all(
    const int* __restrict__ e0s, const int* __restrict__ e0d,
    const int* __restrict__ e1s, const int* __restrict__ e1d,
    const int* __restrict__ e2s, const int* __restrict__ e2d,
    const int* __restrict__ er0, const int* __restrict__ er1,
    const int* __restrict__ er2,
    const int* __restrict__ rp0, const int* __restrict__ rp1,
    const int* __restrict__ rp2,
    int* __restrict__ csr0, int* __restrict__ csr1, int* __restrict__ csr2)
{
    const int t = blockIdx.x * 256 + threadIdx.x;
    const int T = FB * 256;
    int ss[8], dd[8], rr[8], pos[8];
    const int* rpp[8];
    int* cp[8];
    bool ok[8];
#pragma unroll
    for (int i = 0; i < 8; ++i) {
        int e = t + i * T;
        ok[i] = e < ET;
        ss[i] = 0; dd[i] = 0; rr[i] = 0; rpp[i] = rp0; cp[i] = csr0;
        if (ok[i]) {
            if (e < kE0) {
                ss[i] = e0s[e]; dd[i] = e0d[e]; rr[i] = er0[e];
            } else if (e < kE0 + kE1) {
                int le = e - kE0;
                ss[i] = e1s[le]; dd[i] = e1d[le]; rr[i] = er1[le];
                rpp[i] = rp1; cp[i] = csr1;
            } else {
                int le = e - kE0 - kE1;
                ss[i] = e2s[le]; dd[i] = e2d[le]; rr[i] = er2[le];
                rpp[i] = rp2; cp[i] = csr2;
            }
        }
    }
#pragma unroll
    for (int i = 0; i < 8; ++i)
        if (ok[i]) pos[i] = rpp[i][dd[i]];
#pragma unroll
    for (int i = 0; i < 8; ++i)
        if (ok[i]) cp[i][pos[i] + rr[i]] = ss[i];
}

// ---------------- gather segment-mean -> bf16 (round-11 exact) --------------
__global__ __launch_bounds__(256) void k_gather_agg_b(
    const unsigned short* __restrict__ h, const int* __restrict__ csr,
    const int* __restrict__ rp_start, const int* __restrict__ cnt,
    unsigned short* __restrict__ agg, int M)
{
    int d = blockIdx.x * 4 + (threadIdx.x >> 6);
    if (d >= M) return;
    const int lane = threadIdx.x & 63;
    const int half = lane >> 5;
    const int l32 = lane & 31;
    int c = cnt[d], start = rp_start[d], end = start + c;
    float a[8] = {0.f, 0.f, 0.f, 0.f, 0.f, 0.f, 0.f, 0.f};
    for (int chunk = start; chunk < end; chunk += 64) {
        int n = end - chunk; if (n > 64) n = 64;
        int mysrc = (lane < n) ? csr[chunk + lane] : 0;
#pragma unroll 4
        for (int e = 0; e < n; e += 2) {
            int ie = e + half;
            int s = __shfl(mysrc, ie, 64);
            if (ie < n) {
                uint4 v = *reinterpret_cast<const uint4*>(
                    h + (size_t)s * 256 + l32 * 8);
                a[0] += bu2f_lo(v.x); a[1] += bu2f_hi(v.x);
                a[2] += bu2f_lo(v.y); a[3] += bu2f_hi(v.y);
                a[4] += bu2f_lo(v.z); a[5] += bu2f_hi(v.z);
                a[6] += bu2f_lo(v.w); a[7] += bu2f_hi(v.w);
            }
        }
    }
#pragma unroll
    for (int j = 0; j < 8; ++j) a[j] += __shfl(a[j], lane ^ 32, 64);
    if (half == 0) {
        float inv = 1.0f / (float)(c > 1 ? c : 1);
        uint4 o;
        o.x = (unsigned)f2bu(a[0] * inv) | ((unsigned)f2bu(a[1] * inv) << 16);
        o.y = (unsigned)f2bu(a[2] * inv) | ((unsigned)f2bu(a[3] * inv) << 16);
        o.z = (unsigned)f2bu(a[4] * inv) | ((unsigned)f2bu(a[5] * inv) << 16);
        o.w = (unsigned)f2bu(a[6] * inv) | ((unsigned)f2bu(a[7] * inv) << 16);
        *reinterpret_cast<uint4*>(agg + (size_t)d * 256 + l32 * 8) = o;
    }
}

// f32-src fallback (small-ws path)
__global__ __launch_bounds__(256) void k_gather_agg_f(
    const float* __restrict__ h, const int* __restrict__ csr,
    const int* __restrict__ rp_start, const int* __restrict__ cnt,
    unsigned short* __restrict__ agg, int M)
{
    int d = blockIdx.x * 4 + (threadIdx.x >> 6);
    if (d >= M) return;
    int lane = threadIdx.x & 63;
    int c = cnt[d], start = rp_start[d], end = start + c;
    float a0 = 0.f, a1 = 0.f, a2 = 0.f, a3 = 0.f;
    for (int chunk = start; chunk < end; chunk += 64) {
        int n = end - chunk; if (n > 64) n = 64;
        int mysrc = (lane < n) ? csr[chunk + lane] : 0;
#pragma unroll 4
        for (int e = 0; e < n; ++e) {
            int s = __shfl(mysrc, e, 64);
            float4 v = reinterpret_cast<const float4*>(h + (size_t)s * 256)[lane];
            a0 += v.x; a1 += v.y; a2 += v.z; a3 += v.w;
        }
    }
    float inv = 1.0f / (float)(c > 1 ? c : 1);
    ushort4 o;
    o.x = f2bu(a0 * inv); o.y = f2bu(a1 * inv);
    o.z = f2bu(a2 * inv); o.w = f2bu(a3 * inv);
    *reinterpret_cast<ushort4*>(agg + (size_t)d * 256 + lane * 4) = o;
}

// ---------------- MFMA dual-GEMM: out = act([A0|A1] @ WT^T + b) ----------------
template <int ACT, bool A0F32, bool OUTF32>
__global__ __launch_bounds__(256) void k_mfma_gemm(
    const void* __restrict__ A0v, const unsigned short* __restrict__ A1,
    const unsigned short* __restrict__ WT, const float* __restrict__ bias,
    void* __restrict__ outv, int M, int N)
{
    __shared__ unsigned short sA[128 * 72];
    __shared__ unsigned short sB[128 * 72];
    const int tid = threadIdx.x;
    const int lane = tid & 63;
    const int w = tid >> 6;
    const int wr = w >> 1, wc = w & 1;
    const int row0 = blockIdx.x * 128;
    const int col0 = blockIdx.y * 128;

    f32x4 acc[4][4] = {};

    for (int p = 0; p < 8; ++p) {
        const int kc0 = p * 64;
        if (kc0 < 256) {
            if constexpr (A0F32) {
                const float* src = (const float*)A0v;
#pragma unroll
                for (int ps = 0; ps < 8; ++ps) {
                    int flat = (ps * 256 + tid) * 4;
                    int r = flat >> 6, cc = flat & 63;
                    int row = row0 + r; row = row < M ? row : M - 1;
                    float4 v = *reinterpret_cast<const float4*>(
                        src + (size_t)row * 256 + kc0 + cc);
                    ushort4 b4;
                    b4.x = f2bu(v.x); b4.y = f2bu(v.y);
                    b4.z = f2bu(v.z); b4.w = f2bu(v.w);
                    *reinterpret_cast<ushort4*>(&sA[r * 72 + cc]) = b4;
                }
            } else {
                const unsigned short* src = (const unsigned short*)A0v;
#pragma unroll
                for (int ps = 0; ps < 4; ++ps) {
                    int f8 = ps * 256 + tid;
                    int r = f8 >> 3, c8 = f8 & 7;
                    int row = row0 + r; row = row < M ? row : M - 1;
                    uint4 v = *reinterpret_cast<const uint4*>(
                        src + (size_t)row * 256 + kc0 + c8 * 8);
                    *reinterpret_cast<uint4*>(&sA[r * 72 + c8 * 8]) = v;
                }
            }
        } else {
#pragma unroll
            for (int ps = 0; ps < 4; ++ps) {
                int f8 = ps * 256 + tid;
                int r = f8 >> 3, c8 = f8 & 7;
                int row = row0 + r; row = row < M ? row : M - 1;
                uint4 v = *reinterpret_cast<const uint4*>(
                    A1 + (size_t)row * 256 + (kc0 - 256) + c8 * 8);
                *reinterpret_cast<uint4*>(&sA[r * 72 + c8 * 8]) = v;
            }
        }
#pragma unroll
        for (int ps = 0; ps < 4; ++ps) {
            int f8 = ps * 256 + tid;
            int r = f8 >> 3, c8 = f8 & 7;
            uint4 v = *reinterpret_cast<const uint4*>(
                WT + (size_t)(col0 + r) * 512 + kc0 + c8 * 8);
            *reinterpret_cast<uint4*>(&sB[r * 72 + c8 * 8]) = v;
        }
        __syncthreads();
#pragma unroll
        for (int ks = 0; ks < 64; ks += 32) {
            const int lr = lane & 15;
            const int kk = ks + (lane >> 4) * 8;
            bf8v af[4], bfr[4];
#pragma unroll
            for (int m = 0; m < 4; ++m)
                af[m] = *reinterpret_cast<const bf8v*>(
                    &sA[(wr * 64 + m * 16 + lr) * 72 + kk]);
#pragma unroll
            for (int n = 0; n < 4; ++n)
                bfr[n] = *reinterpret_cast<const bf8v*>(
                    &sB[(wc * 64 + n * 16 + lr) * 72 + kk]);
#pragma unroll
            for (int m = 0; m < 4; ++m)
#pragma unroll
                for (int n = 0; n < 4; ++n)
                    acc[m][n] = __builtin_amdgcn_mfma_f32_16x16x32_bf16(
                        af[m], bfr[n], acc[m][n], 0, 0, 0);
        }
        __syncthreads();
    }

    const int lc = lane & 15;
    const int lr4 = (lane >> 4) * 4;
#pragma unroll
    for (int n = 0; n < 4; ++n) {
        int col = col0 + wc * 64 + n * 16 + lc;
        float bb = bias[col];
#pragma unroll
        for (int m = 0; m < 4; ++m) {
#pragma unroll
            for (int j = 0; j < 4; ++j) {
                int row = row0 + wr * 64 + m * 16 + lr4 + j;
                if (row < M) {
                    float v = acc[m][n][j] + bb;
                    if (ACT) v = fmaxf(v, 0.f);
                    if constexpr (OUTF32)
                        ((float*)outv)[(size_t)row * N + col] = v;
                    else
                        ((unsigned short*)outv)[(size_t)row * N + col] = f2bu(v);
                }
            }
        }
    }
}

extern "C" void kernel_launch(void* const* d_in, const int* in_sizes, int n_in,
                              void* d_out, int out_size, void* d_ws, size_t ws_size,
                              hipStream_t stream) {
    const float* feat = (const float*)d_in[0];
    const int* e0s = (const int*)d_in[1];
    const int* e0d = (const int*)d_in[2];
    const int* e1s = (const int*)d_in[3];
    const int* e1d = (const int*)d_in[4];
    const int* e2s = (const int*)d_in[5];
    const int* e2d = (const int*)d_in[6];
    const float* ws0 = (const float*)d_in[7];
    const float* wn0 = (const float*)d_in[8];
    const float* b0 = (const float*)d_in[9];
    const float* ws1 = (const float*)d_in[10];
    const float* wn1 = (const float*)d_in[11];
    const float* b1 = (const float*)d_in[12];
    const float* ws2 = (const float*)d_in[13];
    const float* wn2 = (const float*)d_in[14];
    const float* b2 = (const float*)d_in[15];
    float* out = (float*)d_out;

    char* base = (char*)d_ws;
    const bool big = ws_size >= 345000000ull;
    unsigned short* featbf = nullptr;
    size_t off = 0;
    if (big) { featbf = (unsigned short*)base; off += 204800000ull; }
    unsigned short* aggb = (unsigned short*)(base + off); off += 51200000ull;
    unsigned short* h1b  = (unsigned short*)(base + off); off += 51200000ull;
    unsigned short* h2b  = (unsigned short*)(base + off); off += 10240000ull;
    unsigned short* wt0  = (unsigned short*)(base + off); off += 262144ull;
    unsigned short* wt1  = (unsigned short*)(base + off); off += 262144ull;
    unsigned short* wt2  = (unsigned short*)(base + off); off += 131072ull;
    int* csr0 = (int*)(base + off); off += 6000000ull;
    int* csr1 = (int*)(base + off); off += 800000ull;
    int* csr2 = (int*)(base + off); off += 163840ull;
    // zeroed region: cnt0|cnt1|cnt2 (496384 B)
    int* cnt0 = (int*)(base + off); off += 400000ull;
    int* cnt1 = (int*)(base + off); off += 80000ull;
    int* cnt2 = (int*)(base + off); off += 16384ull;
    int* rp0  = (int*)(base + off); off += 400000ull;
    int* rp1  = (int*)(base + off); off += 80000ull;
    int* rp2  = (int*)(base + off); off += 16384ull;
    int* er0  = (int*)(base + off); off += 6000000ull;
    int* er1  = (int*)(base + off); off += 800000ull;
    int* er2  = (int*)(base + off); off += 163840ull;

    k_zero<<<ZB, 256, 0, stream>>>((int4*)cnt0);

    if (big)
        k_phase0<true><<<CB + C0B + C1B + C2B + PW0B + PW1B + PW2B, 256, 0, stream>>>(
            (const float4*)feat, (uint4*)featbf, e0d, e1d, e2d,
            cnt0, cnt1, cnt2, er0, er1, er2,
            ws0, wn0, ws1, wn1, ws2, wn2, wt0, wt1, wt2);
    else
        k_phase0<false><<<C0B + C1B + C2B + PW0B + PW1B + PW2B, 256, 0, stream>>>(
            nullptr, nullptr, e0d, e1d, e2d,
            cnt0, cnt1, cnt2, er0, er1, er2,
            ws0, wn0, ws1, wn1, ws2, wn2, wt0, wt1, wt2);

    k_scan_apply<<<BSCAN, 256, 0, stream>>>(
        cnt0, cnt1, cnt2, rp0, rp1, rp2);
    k_fill_all<<<FB, 256, 0, stream>>>(
        e0s, e0d, e1s, e1d, e2s, e2d,
        er0, er1, er2, rp0, rp1, rp2, csr0, csr1, csr2);

    // ---- layer 0 ----
    if (big) {
        k_gather_agg_b<<<(kN1 + 3) / 4, 256, 0, stream>>>(
            featbf, csr0, rp0, cnt0, aggb, kN1);
        k_mfma_gemm<1, false, false><<<dim3(782, 2), 256, 0, stream>>>(
            featbf, aggb, wt0, b0, h1b, kN1, 256);
    } else {
        k_gather_agg_f<<<(kN1 + 3) / 4, 256, 0, stream>>>(
            feat, csr0, rp0, cnt0, aggb, kN1);
        k_mfma_gemm<1, true, false><<<dim3(782, 2), 256, 0, stream>>>(
            feat, aggb, wt0, b0, h1b, kN1, 256);
    }

    // ---- layer 1 ----
    k_gather_agg_b<<<(kN2 + 3) / 4, 256, 0, stream>>>(
        h1b, csr1, rp1, cnt1, aggb, kN2);
    k_mfma_gemm<1, false, false><<<dim3(157, 2), 256, 0, stream>>>(
        h1b, aggb, wt1, b1, h2b, kN2, 256);

    // ---- layer 2 ----
    k_gather_agg_b<<<(kN3 + 3) / 4, 256, 0, stream>>>(
        h2b, csr2, rp2, cnt2, aggb, kN3);
    k_mfma_gemm<0, false, true><<<dim3(32, 1), 256, 0, stream>>>(
        h2b, aggb, wt2, b2, out, kN3, 128);
}

// Round 14
// 471.448 us; speedup vs baseline: 1.0905x; 1.0324x over previous
//
#include <hip/hip_runtime.h>
#include <hip/hip_bf16.h>

// GraphSAGE 3-layer, eval mode.
// Round 14: revert to round-11 exact (best measured: 473.5us).
// r12/r13 A/B showed: merged scan_apply = +13us (serial predecessor-sum
// loop at 1 block/CU exposes load latency); nt-stores + unroll8 = +27us.
// Structure: zero | phase0(cast||count+rank||prep) | bsum | bapply |
// fill(atomic-free via erank) | 3x(gather, mfma-gemm). 11 dispatches.

static constexpr int kN1 = 100000, kN2 = 20000, kN3 = 4096;
static constexpr int kE0 = 1500000, kE1 = 200000, kE2 = 40960;

using bf8v  = __attribute__((ext_vector_type(8))) short;   // 8 bf16 (4 VGPR)
using f32x4 = __attribute__((ext_vector_type(4))) float;   // MFMA acc

__device__ __forceinline__ unsigned short f2bu(float f) {
    __hip_bfloat16 h = __float2bfloat16(f);
    return *reinterpret_cast<unsigned short*>(&h);
}
__device__ __forceinline__ float bu2f_lo(unsigned u) {
    unsigned b = u << 16; return *reinterpret_cast<float*>(&b);
}
__device__ __forceinline__ float bu2f_hi(unsigned u) {
    unsigned b = u & 0xffff0000u; return *reinterpret_cast<float*>(&b);
}

// section block counts
static constexpr int CB  = 50000;                 // cast: 12.8M uint4 / 256
static constexpr int C0B = (kE0 + 255) / 256;     // 5860
static constexpr int C1B = (kE1 + 255) / 256;     // 782
static constexpr int C2B = (kE2 + 255) / 256;     // 160
static constexpr int PW0B = 512, PW1B = 512, PW2B = 256;
// scan geometry (int4s per layer)
static constexpr int M4_0 = kN1 / 4, M4_1 = kN2 / 4, M4_2 = kN3 / 4;
static constexpr int B0 = (M4_0 + 255) / 256;     // 98
static constexpr int B1 = (M4_1 + 255) / 256;     // 20
static constexpr int B2 = (M4_2 + 255) / 256;     // 4
static constexpr int BSCAN = B0 + B1 + B2;        // 122
// zero region: cnt0|cnt1|cnt2 = 496384 B
static constexpr int ZN4 = 496384 / 16;           // 31024 int4
static constexpr int ZB  = (ZN4 + 255) / 256;     // 122
// fill geometry: 8 edges/thread
static constexpr int ET = kE0 + kE1 + kE2;        // 1740960
static constexpr int FB = (ET / 8 + 255) / 256;   // 851 blocks

// ---------------- zero cnt region ----------------
__global__ __launch_bounds__(256) void k_zero(int4* __restrict__ p)
{
    int i = blockIdx.x * 256 + threadIdx.x;
    if (i < ZN4) p[i] = make_int4(0, 0, 0, 0);
}

// ---------------- phase 0: cast || count+rank x3 || weight-prep x3 ----------
template <bool BIG>
__global__ __launch_bounds__(256) void k_phase0(
    const float4* __restrict__ feat4, uint4* __restrict__ featbf,
    const int* __restrict__ e0d, const int* __restrict__ e1d,
    const int* __restrict__ e2d,
    int* __restrict__ cnt0, int* __restrict__ cnt1, int* __restrict__ cnt2,
    int* __restrict__ er0, int* __restrict__ er1, int* __restrict__ er2,
    const float* __restrict__ ws0, const float* __restrict__ wn0,
    const float* __restrict__ ws1, const float* __restrict__ wn1,
    const float* __restrict__ ws2, const float* __restrict__ wn2,
    unsigned short* __restrict__ wt0, unsigned short* __restrict__ wt1,
    unsigned short* __restrict__ wt2)
{
    int b = blockIdx.x;
    const int tid = threadIdx.x;
    if (BIG) {
        if (b < CB) {
            int i = b * 256 + tid;
            float4 a = feat4[2 * i], c = feat4[2 * i + 1];
            uint4 o;
            o.x = (unsigned)f2bu(a.x) | ((unsigned)f2bu(a.y) << 16);
            o.y = (unsigned)f2bu(a.z) | ((unsigned)f2bu(a.w) << 16);
            o.z = (unsigned)f2bu(c.x) | ((unsigned)f2bu(c.y) << 16);
            o.w = (unsigned)f2bu(c.z) | ((unsigned)f2bu(c.w) << 16);
            featbf[i] = o;
            return;
        }
        b -= CB;
    }
    if (b < C0B) {
        int e = b * 256 + tid;
        if (e < kE0) er0[e] = atomicAdd(cnt0 + e0d[e], 1);
        return;
    }
    b -= C0B;
    if (b < C1B) {
        int e = b * 256 + tid;
        if (e < kE1) er1[e] = atomicAdd(cnt1 + e1d[e], 1);
        return;
    }
    b -= C1B;
    if (b < C2B) {
        int e = b * 256 + tid;
        if (e < kE2) er2[e] = atomicAdd(cnt2 + e2d[e], 1);
        return;
    }
    b -= C2B;
    if (b < PW0B) {
        int idx = b * 256 + tid;
        int n = idx >> 9, k = idx & 511;
        wt0[idx] = f2bu(k < 256 ? ws0[k * 256 + n] : wn0[(k - 256) * 256 + n]);
        return;
    }
    b -= PW0B;
    if (b < PW1B) {
        int idx = b * 256 + tid;
        int n = idx >> 9, k = idx & 511;
        wt1[idx] = f2bu(k < 256 ? ws1[k * 256 + n] : wn1[(k - 256) * 256 + n]);
        return;
    }
    b -= PW1B;
    {
        int idx = b * 256 + tid;
        int n = idx >> 9, k = idx & 511;
        wt2[idx] = f2bu(k < 256 ? ws2[k * 128 + n] : wn2[(k - 256) * 128 + n]);
    }
}

// ---------------- scan phase 1: per-1024-int block sums ---------------------
__global__ __launch_bounds__(256) void k_bsum_all(
    const int* __restrict__ cnt0, const int* __restrict__ cnt1,
    const int* __restrict__ cnt2, int* __restrict__ bsum)
{
    const int* cnt; int lb, M4, bo;
    int b = blockIdx.x;
    if (b < B0)            { cnt = cnt0; lb = b;            M4 = M4_0; bo = 0; }
    else if (b < B0 + B1)  { cnt = cnt1; lb = b - B0;       M4 = M4_1; bo = B0; }
    else                   { cnt = cnt2; lb = b - B0 - B1;  M4 = M4_2; bo = B0 + B1; }
    __shared__ int wsum[4];
    int idx = lb * 256 + threadIdx.x;
    int ts = 0;
    if (idx < M4) {
        int4 v = reinterpret_cast<const int4*>(cnt)[idx];
        ts = v.x + v.y + v.z + v.w;
    }
#pragma unroll
    for (int off = 32; off > 0; off >>= 1) ts += __shfl_down(ts, off, 64);
    if ((threadIdx.x & 63) == 0) wsum[threadIdx.x >> 6] = ts;
    __syncthreads();
    if (threadIdx.x == 0)
        bsum[bo + lb] = wsum[0] + wsum[1] + wsum[2] + wsum[3];
}

// ---------------- scan phase 2+3 fused: redundant bsum scan + apply ---------
__global__ __launch_bounds__(256) void k_bapply_all(
    const int* __restrict__ cnt0, const int* __restrict__ cnt1,
    const int* __restrict__ cnt2, const int* __restrict__ bsum,
    int* __restrict__ rp0, int* __restrict__ rp1, int* __restrict__ rp2)
{
    const int* cnt; int* rp; int lb, M4, lo;
    int b = blockIdx.x;
    if (b < B0)            { cnt = cnt0; rp = rp0; lb = b;           M4 = M4_0; lo = 0; }
    else if (b < B0 + B1)  { cnt = cnt1; rp = rp1; lb = b - B0;      M4 = M4_1; lo = B0; }
    else                   { cnt = cnt2; rp = rp2; lb = b - B0 - B1; M4 = M4_2; lo = B0 + B1; }
    __shared__ int sscan[BSCAN];
    __shared__ int wsum[4];
    __shared__ int wexcl[4];
    __shared__ int blockbase;
    const int tid = threadIdx.x;
    const int lane = tid & 63;
    const int wid = tid >> 6;
    if (tid < BSCAN) sscan[tid] = bsum[tid];
    __syncthreads();
    if (tid == 0) {
        int s = 0;
        for (int i = lo; i < lo + lb; ++i) s += sscan[i];
        blockbase = s;
    }
    int idx = lb * 256 + tid;
    int4 v = make_int4(0, 0, 0, 0);
    if (idx < M4) v = reinterpret_cast<const int4*>(cnt)[idx];
    int ts = v.x + v.y + v.z + v.w;
    int incl = ts;
#pragma unroll
    for (int off = 1; off < 64; off <<= 1) {
        int t = __shfl_up(incl, off, 64);
        if (lane >= off) incl += t;
    }
    if (lane == 63) wsum[wid] = incl;
    __syncthreads();
    if (tid < 4) {
        int e = 0;
        for (int i = 0; i < tid; ++i) e += wsum[i];
        wexcl[tid] = e;
    }
    __syncthreads();
    if (idx < M4) {
        int base = blockbase + wexcl[wid] + (incl - ts);
        int4 o;
        o.x = base;
        o.y = base + v.x;
        o.z = base + v.x + v.y;
        o.w = base + v.x + v.y + v.z;
        reinterpret_cast<int4*>(rp)[idx] = o;
    }
}

// ---------------- fill: NO atomics. csr[rp[d]+erank[e]] = src[e] ------------
__global__ __launch_bounds__(256) void k_fill_all(
    const int* __restrict__ e0s, const int* __restrict__ e0d,
    const int* __restrict__ e1s, const int* __restrict__ e1d,
    const int* __restrict__ e2s, const int* __restrict__ e2d,
    const int* __restrict__ er0, const int* __restrict__ er1,
    const int* __restrict__ er2,
    const int* __restrict__ rp0, const int* __restrict__ rp1,
    const int* __restrict__ rp2,
    int* __restrict__ csr0, int* __restrict__ csr1, int* __restrict__ csr2)
{
    const int t = blockIdx.x * 256 + threadIdx.x;
    const int T = FB * 256;
    int ss[8], dd[8], rr[8], pos[8];
    const int* rpp[8];
    int* cp[8];
    bool ok[8];
#pragma unroll
    for (int i = 0; i < 8; ++i) {
        int e = t + i * T;
        ok[i] = e < ET;
        ss[i] = 0; dd[i] = 0; rr[i] = 0; rpp[i] = rp0; cp[i] = csr0;
        if (ok[i]) {
            if (e < kE0) {
                ss[i] = e0s[e]; dd[i] = e0d[e]; rr[i] = er0[e];
            } else if (e < kE0 + kE1) {
                int le = e - kE0;
                ss[i] = e1s[le]; dd[i] = e1d[le]; rr[i] = er1[le];
                rpp[i] = rp1; cp[i] = csr1;
            } else {
                int le = e - kE0 - kE1;
                ss[i] = e2s[le]; dd[i] = e2d[le]; rr[i] = er2[le];
                rpp[i] = rp2; cp[i] = csr2;
            }
        }
    }
#pragma unroll
    for (int i = 0; i < 8; ++i)
        if (ok[i]) pos[i] = rpp[i][dd[i]];     // 8 independent random loads
#pragma unroll
    for (int i = 0; i < 8; ++i)
        if (ok[i]) cp[i][pos[i] + rr[i]] = ss[i];
}

// ---------------- gather segment-mean -> bf16 (bf16 src) --------------------
// rp_start[d] = start offset (unmutated), end = start + cnt[d]
__global__ __launch_bounds__(256) void k_gather_agg_b(
    const unsigned short* __restrict__ h, const int* __restrict__ csr,
    const int* __restrict__ rp_start, const int* __restrict__ cnt,
    unsigned short* __restrict__ agg, int M)
{
    int d = blockIdx.x * 4 + (threadIdx.x >> 6);
    if (d >= M) return;
    const int lane = threadIdx.x & 63;
    const int half = lane >> 5;
    const int l32 = lane & 31;
    int c = cnt[d], start = rp_start[d], end = start + c;
    float a[8] = {0.f, 0.f, 0.f, 0.f, 0.f, 0.f, 0.f, 0.f};
    for (int chunk = start; chunk < end; chunk += 64) {
        int n = end - chunk; if (n > 64) n = 64;
        int mysrc = (lane < n) ? csr[chunk + lane] : 0;
#pragma unroll 4
        for (int e = 0; e < n; e += 2) {
            int ie = e + half;
            int s = __shfl(mysrc, ie, 64);
            if (ie < n) {
                uint4 v = *reinterpret_cast<const uint4*>(
                    h + (size_t)s * 256 + l32 * 8);
                a[0] += bu2f_lo(v.x); a[1] += bu2f_hi(v.x);
                a[2] += bu2f_lo(v.y); a[3] += bu2f_hi(v.y);
                a[4] += bu2f_lo(v.z); a[5] += bu2f_hi(v.z);
                a[6] += bu2f_lo(v.w); a[7] += bu2f_hi(v.w);
            }
        }
    }
#pragma unroll
    for (int j = 0; j < 8; ++j) a[j] += __shfl(a[j], lane ^ 32, 64);
    if (half == 0) {
        float inv = 1.0f / (float)(c > 1 ? c : 1);
        uint4 o;
        o.x = (unsigned)f2bu(a[0] * inv) | ((unsigned)f2bu(a[1] * inv) << 16);
        o.y = (unsigned)f2bu(a[2] * inv) | ((unsigned)f2bu(a[3] * inv) << 16);
        o.z = (unsigned)f2bu(a[4] * inv) | ((unsigned)f2bu(a[5] * inv) << 16);
        o.w = (unsigned)f2bu(a[6] * inv) | ((unsigned)f2bu(a[7] * inv) << 16);
        *reinterpret_cast<uint4*>(agg + (size_t)d * 256 + l32 * 8) = o;
    }
}

// f32-src fallback (small-ws path)
__global__ __launch_bounds__(256) void k_gather_agg_f(
    const float* __restrict__ h, const int* __restrict__ csr,
    const int* __restrict__ rp_start, const int* __restrict__ cnt,
    unsigned short* __restrict__ agg, int M)
{
    int d = blockIdx.x * 4 + (threadIdx.x >> 6);
    if (d >= M) return;
    int lane = threadIdx.x & 63;
    int c = cnt[d], start = rp_start[d], end = start + c;
    float a0 = 0.f, a1 = 0.f, a2 = 0.f, a3 = 0.f;
    for (int chunk = start; chunk < end; chunk += 64) {
        int n = end - chunk; if (n > 64) n = 64;
        int mysrc = (lane < n) ? csr[chunk + lane] : 0;
#pragma unroll 4
        for (int e = 0; e < n; ++e) {
            int s = __shfl(mysrc, e, 64);
            float4 v = reinterpret_cast<const float4*>(h + (size_t)s * 256)[lane];
            a0 += v.x; a1 += v.y; a2 += v.z; a3 += v.w;
        }
    }
    float inv = 1.0f / (float)(c > 1 ? c : 1);
    ushort4 o;
    o.x = f2bu(a0 * inv); o.y = f2bu(a1 * inv);
    o.z = f2bu(a2 * inv); o.w = f2bu(a3 * inv);
    *reinterpret_cast<ushort4*>(agg + (size_t)d * 256 + lane * 4) = o;
}

// ---------------- MFMA dual-GEMM: out = act([A0|A1] @ WT^T + b) ----------------
template <int ACT, bool A0F32, bool OUTF32>
__global__ __launch_bounds__(256) void k_mfma_gemm(
    const void* __restrict__ A0v, const unsigned short* __restrict__ A1,
    const unsigned short* __restrict__ WT, const float* __restrict__ bias,
    void* __restrict__ outv, int M, int N)
{
    __shared__ unsigned short sA[128 * 72];
    __shared__ unsigned short sB[128 * 72];
    const int tid = threadIdx.x;
    const int lane = tid & 63;
    const int w = tid >> 6;
    const int wr = w >> 1, wc = w & 1;
    const int row0 = blockIdx.x * 128;
    const int col0 = blockIdx.y * 128;

    f32x4 acc[4][4] = {};

    for (int p = 0; p < 8; ++p) {
        const int kc0 = p * 64;
        if (kc0 < 256) {
            if constexpr (A0F32) {
                const float* src = (const float*)A0v;
#pragma unroll
                for (int ps = 0; ps < 8; ++ps) {
                    int flat = (ps * 256 + tid) * 4;
                    int r = flat >> 6, cc = flat & 63;
                    int row = row0 + r; row = row < M ? row : M - 1;
                    float4 v = *reinterpret_cast<const float4*>(
                        src + (size_t)row * 256 + kc0 + cc);
                    ushort4 b4;
                    b4.x = f2bu(v.x); b4.y = f2bu(v.y);
                    b4.z = f2bu(v.z); b4.w = f2bu(v.w);
                    *reinterpret_cast<ushort4*>(&sA[r * 72 + cc]) = b4;
                }
            } else {
                const unsigned short* src = (const unsigned short*)A0v;
#pragma unroll
                for (int ps = 0; ps < 4; ++ps) {
                    int f8 = ps * 256 + tid;
                    int r = f8 >> 3, c8 = f8 & 7;
                    int row = row0 + r; row = row < M ? row : M - 1;
                    uint4 v = *reinterpret_cast<const uint4*>(
                        src + (size_t)row * 256 + kc0 + c8 * 8);
                    *reinterpret_cast<uint4*>(&sA[r * 72 + c8 * 8]) = v;
                }
            }
        } else {
#pragma unroll
            for (int ps = 0; ps < 4; ++ps) {
                int f8 = ps * 256 + tid;
                int r = f8 >> 3, c8 = f8 & 7;
                int row = row0 + r; row = row < M ? row : M - 1;
                uint4 v = *reinterpret_cast<const uint4*>(
                    A1 + (size_t)row * 256 + (kc0 - 256) + c8 * 8);
                *reinterpret_cast<uint4*>(&sA[r * 72 + c8 * 8]) = v;
            }
        }
#pragma unroll
        for (int ps = 0; ps < 4; ++ps) {
            int f8 = ps * 256 + tid;
            int r = f8 >> 3, c8 = f8 & 7;
            uint4 v = *reinterpret_cast<const uint4*>(
                WT + (size_t)(col0 + r) * 512 + kc0 + c8 * 8);
            *reinterpret_cast<uint4*>(&sB[r * 72 + c8 * 8]) = v;
        }
        __syncthreads();
#pragma unroll
        for (int ks = 0; ks < 64; ks += 32) {
            const int lr = lane & 15;
            const int kk = ks + (lane >> 4) * 8;
            bf8v af[4], bfr[4];
#pragma unroll
            for (int m = 0; m < 4; ++m)
                af[m] = *reinterpret_cast<const bf8v*>(
                    &sA[(wr * 64 + m * 16 + lr) * 72 + kk]);
#pragma unroll
            for (int n = 0; n < 4; ++n)
                bfr[n] = *reinterpret_cast<const bf8v*>(
                    &sB[(wc * 64 + n * 16 + lr) * 72 + kk]);
#pragma unroll
            for (int m = 0; m < 4; ++m)
#pragma unroll
                for (int n = 0; n < 4; ++n)
                    acc[m][n] = __builtin_amdgcn_mfma_f32_16x16x32_bf16(
                        af[m], bfr[n], acc[m][n], 0, 0, 0);
        }
        __syncthreads();
    }

    const int lc = lane & 15;
    const int lr4 = (lane >> 4) * 4;
#pragma unroll
    for (int n = 0; n < 4; ++n) {
        int col = col0 + wc * 64 + n * 16 + lc;
        float bb = bias[col];
#pragma unroll
        for (int m = 0; m < 4; ++m) {
#pragma unroll
            for (int j = 0; j < 4; ++j) {
                int row = row0 + wr * 64 + m * 16 + lr4 + j;
                if (row < M) {
                    float v = acc[m][n][j] + bb;
                    if (ACT) v = fmaxf(v, 0.f);
                    if constexpr (OUTF32)
                        ((float*)outv)[(size_t)row * N + col] = v;
                    else
                        ((unsigned short*)outv)[(size_t)row * N + col] = f2bu(v);
                }
            }
        }
    }
}

extern "C" void kernel_launch(void* const* d_in, const int* in_sizes, int n_in,
                              void* d_out, int out_size, void* d_ws, size_t ws_size,
                              hipStream_t stream) {
    const float* feat = (const float*)d_in[0];
    const int* e0s = (const int*)d_in[1];
    const int* e0d = (const int*)d_in[2];
    const int* e1s = (const int*)d_in[3];
    const int* e1d = (const int*)d_in[4];
    const int* e2s = (const int*)d_in[5];
    const int* e2d = (const int*)d_in[6];
    const float* ws0 = (const float*)d_in[7];
    const float* wn0 = (const float*)d_in[8];
    const float* b0 = (const float*)d_in[9];
    const float* ws1 = (const float*)d_in[10];
    const float* wn1 = (const float*)d_in[11];
    const float* b1 = (const float*)d_in[12];
    const float* ws2 = (const float*)d_in[13];
    const float* wn2 = (const float*)d_in[14];
    const float* b2 = (const float*)d_in[15];
    float* out = (float*)d_out;

    char* base = (char*)d_ws;
    const bool big = ws_size >= 345000000ull;
    unsigned short* featbf = nullptr;
    size_t off = 0;
    if (big) { featbf = (unsigned short*)base; off += 204800000ull; }
    unsigned short* aggb = (unsigned short*)(base + off); off += 51200000ull;
    unsigned short* h1b  = (unsigned short*)(base + off); off += 51200000ull;
    unsigned short* h2b  = (unsigned short*)(base + off); off += 10240000ull;
    unsigned short* wt0  = (unsigned short*)(base + off); off += 262144ull;
    unsigned short* wt1  = (unsigned short*)(base + off); off += 262144ull;
    unsigned short* wt2  = (unsigned short*)(base + off); off += 131072ull;
    int* csr0 = (int*)(base + off); off += 6000000ull;
    int* csr1 = (int*)(base + off); off += 800000ull;
    int* csr2 = (int*)(base + off); off += 163840ull;
    // zeroed region: cnt0|cnt1|cnt2 (496384 B)
    int* cnt0 = (int*)(base + off); off += 400000ull;
    int* cnt1 = (int*)(base + off); off += 80000ull;
    int* cnt2 = (int*)(base + off); off += 16384ull;
    int* rp0  = (int*)(base + off); off += 400000ull;
    int* rp1  = (int*)(base + off); off += 80000ull;
    int* rp2  = (int*)(base + off); off += 16384ull;
    int* bsum = (int*)(base + off); off += 512ull;
    int* er0  = (int*)(base + off); off += 6000000ull;
    int* er1  = (int*)(base + off); off += 800000ull;
    int* er2  = (int*)(base + off); off += 163840ull;

    k_zero<<<ZB, 256, 0, stream>>>((int4*)cnt0);

    if (big)
        k_phase0<true><<<CB + C0B + C1B + C2B + PW0B + PW1B + PW2B, 256, 0, stream>>>(
            (const float4*)feat, (uint4*)featbf, e0d, e1d, e2d,
            cnt0, cnt1, cnt2, er0, er1, er2,
            ws0, wn0, ws1, wn1, ws2, wn2, wt0, wt1, wt2);
    else
        k_phase0<false><<<C0B + C1B + C2B + PW0B + PW1B + PW2B, 256, 0, stream>>>(
            nullptr, nullptr, e0d, e1d, e2d,
            cnt0, cnt1, cnt2, er0, er1, er2,
            ws0, wn0, ws1, wn1, ws2, wn2, wt0, wt1, wt2);

    k_bsum_all<<<BSCAN, 256, 0, stream>>>(cnt0, cnt1, cnt2, bsum);
    k_bapply_all<<<BSCAN, 256, 0, stream>>>(
        cnt0, cnt1, cnt2, bsum, rp0, rp1, rp2);
    k_fill_all<<<FB, 256, 0, stream>>>(
        e0s, e0d, e1s, e1d, e2s, e2d,
        er0, er1, er2, rp0, rp1, rp2, csr0, csr1, csr2);

    // ---- layer 0 ----
    if (big) {
        k_gather_agg_b<<<(kN1 + 3) / 4, 256, 0, stream>>>(
            featbf, csr0, rp0, cnt0, aggb, kN1);
        k_mfma_gemm<1, false, false><<<dim3(782, 2), 256, 0, stream>>>(
            featbf, aggb, wt0, b0, h1b, kN1, 256);
    } else {
        k_gather_agg_f<<<(kN1 + 3) / 4, 256, 0, stream>>>(
            feat, csr0, rp0, cnt0, aggb, kN1);
        k_mfma_gemm<1, true, false><<<dim3(782, 2), 256, 0, stream>>>(
            feat, aggb, wt0, b0, h1b, kN1, 256);
    }

    // ---- layer 1 ----
    k_gather_agg_b<<<(kN2 + 3) / 4, 256, 0, stream>>>(
        h1b, csr1, rp1, cnt1, aggb, kN2);
    k_mfma_gemm<1, false, false><<<dim3(157, 2), 256, 0, stream>>>(
        h1b, aggb, wt1, b1, h2b, kN2, 256);

    // ---- layer 2 ----
    k_gather_agg_b<<<(kN3 + 3) / 4, 256, 0, stream>>>(
        h2b, csr2, rp2, cnt2, aggb, kN3);
    k_mfma_gemm<0, false, true><<<dim3(32, 1), 256, 0, stream>>>(
        h2b, aggb, wt2, b2, out, kN3, 128);
}